// Round 6
// baseline (117.025 us; speedup 1.0000x reference)
//
#include <hip/hip_runtime.h>

#define LOG2E 1.4426950408889634f
#define K_SCALE 2.8853900817779268f   // 2*log2(e)

typedef __attribute__((ext_vector_type(8))) short bf16x8;
typedef __attribute__((ext_vector_type(4))) float f32x4;

constexpr int Bn = 4, LXn = 384, LYn = 384, Hn = 256, Fn = 512;

__device__ inline unsigned short bf16rn(float f) {
  unsigned u = __builtin_bit_cast(unsigned, f);
  u += 0x7fff + ((u >> 16) & 1);             // round-to-nearest-even
  return (unsigned short)(u >> 16);
}
__device__ inline float bf16tof(unsigned short h) {
  return __builtin_bit_cast(float, (unsigned)h << 16);
}

// ---------------------------------------------------------------- kernel 1
// One-shot f32 -> bf16 hi/lo split of y, Wm, x (row-major planes), plus
// transposed xT planes for qtm's B operand. Pure memory-bound (~17 MB).
__global__ __launch_bounds__(256) void split_k(
    const float* __restrict__ x, const float* __restrict__ y,
    const float* __restrict__ Wm,
    unsigned short* __restrict__ yh, unsigned short* __restrict__ yl,
    unsigned short* __restrict__ wh, unsigned short* __restrict__ wl,
    unsigned short* __restrict__ xh, unsigned short* __restrict__ xl,
    unsigned short* __restrict__ xTh, unsigned short* __restrict__ xTl)
{
  const int tid = threadIdx.x;
  const int bid = blockIdx.x;

  if (bid < 256) {                        // ---- elementwise split path ----
    // float4-quads: y 196608 | Wm 32768 | x 196608  (total 425984)
    for (int q = bid * 256 + tid; q < 425984; q += 65536) {
      const float* src; unsigned short *dh, *dl; size_t off;
      if (q < 196608)      { off = (size_t)q * 4;            src = y  + off; dh = yh; dl = yl; }
      else if (q < 229376) { off = (size_t)(q - 196608) * 4; src = Wm + off; dh = wh; dl = wl; }
      else                 { off = (size_t)(q - 229376) * 4; src = x  + off; dh = xh; dl = xl; }
      float4 v = *(const float4*)src;
      const float* vv = (const float*)&v;
      unsigned short h[4], l[4];
      #pragma unroll
      for (int i = 0; i < 4; ++i) {
        h[i] = bf16rn(vv[i]);
        l[i] = bf16rn(vv[i] - bf16tof(h[i]));
      }
      *(uint2*)&dh[off] = *(uint2*)&h[0];
      *(uint2*)&dl[off] = *(uint2*)&l[0];
    }
    return;
  }

  // ---- x transpose path: 192 blocks, 64x64 tiles ----
  __shared__ float T[64 * 65];
  const int pid = bid - 256;
  const int b = pid / 48, t = pid % 48;
  const int l0 = (t / 8) * 64, f0 = (t % 8) * 64;
  const int r = tid >> 2, cq = (tid & 3) * 16;
  const float* xp = x + ((size_t)(b * LXn + l0 + r)) * Fn + f0 + cq;
  #pragma unroll
  for (int q = 0; q < 4; ++q) {
    float4 v = *(const float4*)(xp + q * 4);
    T[r * 65 + cq + q * 4 + 0] = v.x; T[r * 65 + cq + q * 4 + 1] = v.y;
    T[r * 65 + cq + q * 4 + 2] = v.z; T[r * 65 + cq + q * 4 + 3] = v.w;
  }
  __syncthreads();
  const int fr = tid >> 2, lq = (tid & 3) * 16;
  unsigned short hi[16], lo[16];
  #pragma unroll
  for (int i = 0; i < 16; ++i) {
    float v = T[(lq + i) * 65 + fr];
    hi[i] = bf16rn(v);
    lo[i] = bf16rn(v - bf16tof(hi[i]));
  }
  size_t o = ((size_t)(b * Fn + f0 + fr)) * LXn + l0 + lq;
  *(uint4*)&xTh[o] = *(uint4*)&hi[0]; *(uint4*)&xTh[o + 8] = *(uint4*)&hi[8];
  *(uint4*)&xTl[o] = *(uint4*)&lo[0]; *(uint4*)&xTl[o + 8] = *(uint4*)&lo[8];
}

// ---------------------------------------------------------------- kernel 2
// Zero-LDS, zero-barrier 3-product bf16 MFMA GEMM + exp2 epilogue.
// Fragments loaded directly from global: lanes {r,r+16,r+32,r+48} of a b128
// load cover one 64B line of row r -> 16 full lines per wave-load.
//  blocks [0,96):   ey[(b,j)][h] = exp2(-K * y.Wm^T)  (A=y rows, B=Wm rows)
//  blocks [96,192): exT[b][h][l] = exp2(+K * Wm.x^T)  (A=Wm rows, B=x rows)
__global__ __launch_bounds__(256) void gemm2(
    const unsigned short* __restrict__ yh, const unsigned short* __restrict__ yl,
    const unsigned short* __restrict__ wh, const unsigned short* __restrict__ wl,
    const unsigned short* __restrict__ xh, const unsigned short* __restrict__ xl,
    float* __restrict__ ey, float* __restrict__ exT)
{
  int t = blockIdx.x;
  const unsigned short *Ah, *Al, *Bh, *Bl;
  int m0, n0; float ksc; bool jobA;
  if (t < 96) { jobA = true;  m0 = (t % 24) * 64; n0 = (t / 24) * 64;
                Ah = yh; Al = yl; Bh = wh; Bl = wl; ksc = -K_SCALE; }
  else { t -= 96; jobA = false; m0 = (t & 3) * 64; n0 = (t >> 2) * 64;
                Ah = wh; Al = wl; Bh = xh; Bl = xl; ksc =  K_SCALE; }

  const int tid = threadIdx.x, w = tid >> 6, lane = tid & 63;
  const int quad = lane >> 4, l15 = lane & 15;
  const int mo = (w & 1) * 32, no = (w >> 1) * 32;   // wave tile 32x32
  const size_t ar = (size_t)(m0 + mo + l15) * Fn + quad * 8;
  const size_t br = (size_t)(n0 + no + l15) * Fn + quad * 8;
  f32x4 acc[2][2] = {};

  #pragma unroll 2
  for (int k0 = 0; k0 < Fn; k0 += 32) {
    bf16x8 a_h[2], a_l[2], b_h[2], b_l[2];
    #pragma unroll
    for (int mi = 0; mi < 2; ++mi) {
      a_h[mi] = *(const bf16x8*)&Ah[ar + (size_t)mi * 16 * Fn + k0];
      a_l[mi] = *(const bf16x8*)&Al[ar + (size_t)mi * 16 * Fn + k0];
    }
    #pragma unroll
    for (int nj = 0; nj < 2; ++nj) {
      b_h[nj] = *(const bf16x8*)&Bh[br + (size_t)nj * 16 * Fn + k0];
      b_l[nj] = *(const bf16x8*)&Bl[br + (size_t)nj * 16 * Fn + k0];
    }
    #pragma unroll
    for (int mi = 0; mi < 2; ++mi)
      #pragma unroll
      for (int nj = 0; nj < 2; ++nj) {
        acc[mi][nj] = __builtin_amdgcn_mfma_f32_16x16x32_bf16(a_h[mi], b_h[nj], acc[mi][nj], 0, 0, 0);
        acc[mi][nj] = __builtin_amdgcn_mfma_f32_16x16x32_bf16(a_h[mi], b_l[nj], acc[mi][nj], 0, 0, 0);
        acc[mi][nj] = __builtin_amdgcn_mfma_f32_16x16x32_bf16(a_l[mi], b_h[nj], acc[mi][nj], 0, 0, 0);
      }
  }

  #pragma unroll
  for (int mi = 0; mi < 2; ++mi)
    #pragma unroll
    for (int nj = 0; nj < 2; ++nj)
      #pragma unroll
      for (int rr = 0; rr < 4; ++rr) {
        int row = m0 + mo + mi * 16 + quad * 4 + rr;
        int col = n0 + no + nj * 16 + l15;
        float val = __builtin_amdgcn_exp2f(ksc * acc[mi][nj][rr]);
        if (jobA) ey[(size_t)row * Hn + col] = val;
        else {
          int bb = col / LXn, l = col % LXn;     // 64-aligned tile never straddles b
          exT[(size_t)bb * Hn * LXn + (size_t)row * LXn + l] = val;
        }
      }
}

// ---------------------------------------------------------------- kernel 3
// score_v2 (unchanged from R5): VALU-balanced score + fused softmax.
__global__ __launch_bounds__(768) void score_v2(
    const float* __restrict__ exT, const float* __restrict__ ey,
    const float* __restrict__ vm, unsigned short* __restrict__ ahi,
    unsigned short* __restrict__ alo)
{
  __shared__ float ey6[6 * 256];
  __shared__ float vms[256];
  __shared__ __align__(16) float part[4 * 6 * 384];
  __shared__ float red[768];
  __shared__ float red2[2][48];

  const int tid = threadIdx.x;
  const int b = blockIdx.y, j0 = blockIdx.x * 6;
  const int lq = tid % 96, hg = tid / 96;
  const int hb = hg * 32;

  for (int i = tid; i < 6 * 256; i += 768)
    ey6[i] = ey[(size_t)(b * LYn + j0 + (i >> 8)) * Hn + (i & 255)];
  if (tid < 256) vms[tid] = -2.0f * vm[tid];
  __syncthreads();

  const float* exb = exT + (size_t)b * Hn * LXn + (size_t)hb * LXn + lq * 4;
  float acc[6][4] = {};

  for (int hs = 0; hs < 32; hs += 4) {
    float4 e0 = *(const float4*)(exb + (size_t)(hs + 0) * LXn);
    float4 e1 = *(const float4*)(exb + (size_t)(hs + 1) * LXn);
    float4 e2 = *(const float4*)(exb + (size_t)(hs + 2) * LXn);
    float4 e3 = *(const float4*)(exb + (size_t)(hs + 3) * LXn);
    const float* E0 = (const float*)&e0; const float* E1 = (const float*)&e1;
    const float* E2 = (const float*)&e2; const float* E3 = (const float*)&e3;
    float4 v4 = *(const float4*)&vms[hb + hs];
    #pragma unroll
    for (int j = 0; j < 6; ++j) {
      float4 y4 = *(const float4*)&ey6[j * 256 + hb + hs];
      #pragma unroll
      for (int i = 0; i < 4; ++i) {
        float A = fmaf(E0[i], y4.x, 1.f), B = fmaf(E1[i], y4.y, 1.f);
        float C = fmaf(E2[i], y4.z, 1.f), D = fmaf(E3[i], y4.w, 1.f);
        float AB = A * B, CD = C * D;
        float n1 = fmaf(v4.y, A, v4.x * B), n2 = fmaf(v4.w, C, v4.z * D);
        float num = fmaf(n2, AB, n1 * CD);
        acc[j][i] = fmaf(num, __builtin_amdgcn_rcpf(AB * CD), acc[j][i]);
      }
    }
  }

  if (hg >= 4) {
    #pragma unroll
    for (int j = 0; j < 6; ++j)
      *(float4*)&part[((hg - 4) * 6 + j) * 384 + lq * 4] = *(const float4*)&acc[j][0];
  }
  __syncthreads();
  if (hg < 4) {
    #pragma unroll
    for (int j = 0; j < 6; ++j) {
      float4 o = *(const float4*)&part[(hg * 6 + j) * 384 + lq * 4];
      acc[j][0] += o.x; acc[j][1] += o.y; acc[j][2] += o.z; acc[j][3] += o.w;
      *(float4*)&part[(hg * 6 + j) * 384 + lq * 4] = *(const float4*)&acc[j][0];
    }
  }
  __syncthreads();

  float4 s4 = make_float4(0, 0, 0, 0);
  const int ls = lq;
  if (tid < 576) {
    const int j = tid / 96;
    #pragma unroll
    for (int p = 0; p < 4; ++p) {
      float4 o = *(const float4*)&part[(p * 6 + j) * 384 + ls * 4];
      s4.x += o.x; s4.y += o.y; s4.z += o.z; s4.w += o.w;
    }
    red[tid] = fmaxf(fmaxf(s4.x, s4.y), fmaxf(s4.z, s4.w));
  }
  __syncthreads();
  if (tid < 48) {
    const int j = tid / 8, seg = tid % 8;
    float m = red[j * 96 + seg * 12];
    #pragma unroll
    for (int i = 1; i < 12; ++i) m = fmaxf(m, red[j * 96 + seg * 12 + i]);
    red2[0][tid] = m;
  }
  __syncthreads();
  float4 e4;
  if (tid < 576) {
    const int j = tid / 96;
    float m = red2[0][j * 8];
    #pragma unroll
    for (int i = 1; i < 8; ++i) m = fmaxf(m, red2[0][j * 8 + i]);
    e4.x = __builtin_amdgcn_exp2f((s4.x - m) * LOG2E);
    e4.y = __builtin_amdgcn_exp2f((s4.y - m) * LOG2E);
    e4.z = __builtin_amdgcn_exp2f((s4.z - m) * LOG2E);
    e4.w = __builtin_amdgcn_exp2f((s4.w - m) * LOG2E);
    red[tid] = e4.x + e4.y + e4.z + e4.w;
  }
  __syncthreads();
  if (tid < 48) {
    const int j = tid / 8, seg = tid % 8;
    float t = 0.f;
    #pragma unroll
    for (int i = 0; i < 12; ++i) t += red[j * 96 + seg * 12 + i];
    red2[1][tid] = t;
  }
  __syncthreads();
  if (tid < 576) {
    const int j = tid / 96;
    float tot = 0.f;
    #pragma unroll
    for (int i = 0; i < 8; ++i) tot += red2[1][j * 8 + i];
    float r = __builtin_amdgcn_rcpf(tot);
    unsigned short h[4], l[4];
    const float* ep = (const float*)&e4;
    #pragma unroll
    for (int i = 0; i < 4; ++i) {
      float a = ep[i] * r;
      h[i] = bf16rn(a);
      l[i] = bf16rn(a - bf16tof(h[i]));
    }
    size_t o = (size_t)(b * LYn + j0 + j) * LXn + ls * 4;
    *(uint2*)&ahi[o] = *(uint2*)&h[0];
    *(uint2*)&alo[o] = *(uint2*)&l[0];
  }
}

// ---------------------------------------------------------------- kernel 4
// Zero-LDS qtm: out[b,j,f] = sum_l a[j,l]*x[l,f].
// A = a hi/lo [j][l] row-major, B = xT hi/lo [f][l] row-major -> direct frags.
__global__ __launch_bounds__(256) void qtm(
    const unsigned short* __restrict__ ahi, const unsigned short* __restrict__ alo,
    const unsigned short* __restrict__ xTh, const unsigned short* __restrict__ xTl,
    float* __restrict__ out)
{
  const int t = blockIdx.x;
  const int b = t / 48, t2 = t % 48;
  const int m0 = (t2 % 6) * 64, n0 = (t2 / 6) * 64;   // m over j, n over f
  const int tid = threadIdx.x, w = tid >> 6, lane = tid & 63;
  const int quad = lane >> 4, l15 = lane & 15;
  const int mo = (w & 1) * 32, no = (w >> 1) * 32;
  const size_t ar = (size_t)(b * LYn + m0 + mo + l15) * LXn + quad * 8;
  const size_t br = (size_t)(b * Fn + n0 + no + l15) * LXn + quad * 8;
  f32x4 acc[2][2] = {};

  #pragma unroll 2
  for (int k0 = 0; k0 < LXn; k0 += 32) {
    bf16x8 a_h[2], a_l[2], b_h[2], b_l[2];
    #pragma unroll
    for (int mi = 0; mi < 2; ++mi) {
      a_h[mi] = *(const bf16x8*)&ahi[ar + (size_t)mi * 16 * LXn + k0];
      a_l[mi] = *(const bf16x8*)&alo[ar + (size_t)mi * 16 * LXn + k0];
    }
    #pragma unroll
    for (int nj = 0; nj < 2; ++nj) {
      b_h[nj] = *(const bf16x8*)&xTh[br + (size_t)nj * 16 * LXn + k0];
      b_l[nj] = *(const bf16x8*)&xTl[br + (size_t)nj * 16 * LXn + k0];
    }
    #pragma unroll
    for (int mi = 0; mi < 2; ++mi)
      #pragma unroll
      for (int nj = 0; nj < 2; ++nj) {
        acc[mi][nj] = __builtin_amdgcn_mfma_f32_16x16x32_bf16(a_h[mi], b_h[nj], acc[mi][nj], 0, 0, 0);
        acc[mi][nj] = __builtin_amdgcn_mfma_f32_16x16x32_bf16(a_h[mi], b_l[nj], acc[mi][nj], 0, 0, 0);
        acc[mi][nj] = __builtin_amdgcn_mfma_f32_16x16x32_bf16(a_l[mi], b_h[nj], acc[mi][nj], 0, 0, 0);
      }
  }

  #pragma unroll
  for (int mi = 0; mi < 2; ++mi)
    #pragma unroll
    for (int nj = 0; nj < 2; ++nj)
      #pragma unroll
      for (int rr = 0; rr < 4; ++rr) {
        int row = m0 + mo + mi * 16 + quad * 4 + rr;   // j
        int col = n0 + no + nj * 16 + l15;             // f
        out[((size_t)(b * LYn + row)) * Fn + col] = acc[mi][nj][rr];
      }
}

extern "C" void kernel_launch(void* const* d_in, const int* in_sizes, int n_in,
                              void* d_out, int out_size, void* d_ws, size_t ws_size,
                              hipStream_t stream) {
  const float* x  = (const float*)d_in[0];
  const float* y  = (const float*)d_in[1];
  const float* Wm = (const float*)d_in[2];
  const float* vm = (const float*)d_in[3];
  float* outp = (float*)d_out;

  float* ey  = (float*)d_ws;                            // 393216 f32
  float* exT = ey + 393216;                             // 393216 f32
  unsigned short* p = (unsigned short*)(exT + 393216);
  unsigned short* yh  = p;              p += 786432;    // 1536*512
  unsigned short* yl  = p;              p += 786432;
  unsigned short* wh  = p;              p += 131072;    // 256*512
  unsigned short* wl  = p;              p += 131072;
  unsigned short* xh  = p;              p += 786432;    // 1536*512
  unsigned short* xl  = p;              p += 786432;
  unsigned short* xTh = p;              p += 786432;    // 4*512*384
  unsigned short* xTl = p;              p += 786432;
  unsigned short* ahi = p;              p += 589824;    // 1536*384
  unsigned short* alo = p;                              // total ~15 MB

  hipLaunchKernelGGL(split_k, dim3(448), dim3(256), 0, stream,
                     x, y, Wm, yh, yl, wh, wl, xh, xl, xTh, xTl);
  hipLaunchKernelGGL(gemm2, dim3(192), dim3(256), 0, stream,
                     yh, yl, wh, wl, xh, xl, ey, exT);
  hipLaunchKernelGGL(score_v2, dim3(64, 4), dim3(768), 0, stream, exT, ey, vm, ahi, alo);
  hipLaunchKernelGGL(qtm, dim3(192), dim3(256), 0, stream, ahi, alo, xTh, xTl, outp);
}

// Round 8
// 115.358 us; speedup vs baseline: 1.0145x; 1.0145x over previous
//
#include <hip/hip_runtime.h>

#define LOG2E 1.4426950408889634f
#define K_SCALE 2.8853900817779268f   // 2*log2(e)

typedef __attribute__((ext_vector_type(8))) short bf16x8;
typedef __attribute__((ext_vector_type(4))) float f32x4;

constexpr int Bn = 4, LXn = 384, LYn = 384, Hn = 256, Fn = 512;

__device__ inline unsigned short bf16rn(float f) {
  unsigned u = __builtin_bit_cast(unsigned, f);
  u += 0x7fff + ((u >> 16) & 1);             // round-to-nearest-even
  return (unsigned short)(u >> 16);
}
__device__ inline float bf16tof(unsigned short h) {
  return __builtin_bit_cast(float, (unsigned)h << 16);
}

// ---------------------------------------------------------------- kernel 1
// (R5 k1, unchanged)
// blocks [0,96):   ey[m=(b,j)][h]  = exp2(-K * y.Wm^T)   (MFMA, split-bf16 3-product)
// blocks [96,192): exT[b][h][l]    = exp2(+K * Wm.x^T)
// blocks [192,384): transpose+split x -> xTh/xTl[b][f][l]  (phase-D B operand)
__global__ __launch_bounds__(256) void k1(
    const float* __restrict__ x, const float* __restrict__ y,
    const float* __restrict__ Wm, float* __restrict__ ey, float* __restrict__ exT,
    unsigned short* __restrict__ xTh, unsigned short* __restrict__ xTl)
{
  __shared__ char smem[36864];
  const int tid = threadIdx.x;
  const int bid = blockIdx.x;

  if (bid >= 192) {                       // ---- transpose/split path ----
    float* T = (float*)smem;              // [64][65]
    const int pid = bid - 192;
    const int b = pid / 48, t = pid % 48;
    const int l0 = (t / 8) * 64, f0 = (t % 8) * 64;
    const int r = tid >> 2, cq = (tid & 3) * 16;
    const float* xp = x + ((size_t)(b * LXn + l0 + r)) * Fn + f0 + cq;
    #pragma unroll
    for (int q = 0; q < 4; ++q) {
      float4 v = *(const float4*)(xp + q * 4);
      T[r * 65 + cq + q * 4 + 0] = v.x; T[r * 65 + cq + q * 4 + 1] = v.y;
      T[r * 65 + cq + q * 4 + 2] = v.z; T[r * 65 + cq + q * 4 + 3] = v.w;
    }
    __syncthreads();
    const int fr = tid >> 2, lq = (tid & 3) * 16;
    unsigned short hi[16], lo[16];
    #pragma unroll
    for (int i = 0; i < 16; ++i) {
      float v = T[(lq + i) * 65 + fr];
      hi[i] = bf16rn(v);
      lo[i] = bf16rn(v - bf16tof(hi[i]));
    }
    size_t o = ((size_t)(b * Fn + f0 + fr)) * LXn + l0 + lq;
    *(uint4*)&xTh[o] = *(uint4*)&hi[0]; *(uint4*)&xTh[o + 8] = *(uint4*)&hi[8];
    *(uint4*)&xTl[o] = *(uint4*)&lo[0]; *(uint4*)&xTl[o + 8] = *(uint4*)&lo[8];
    return;
  }

  // ---- MFMA GEMM path ----
  unsigned short* Ah = (unsigned short*)smem;   // [64][72] bf16
  unsigned short* Al = Ah + 64 * 72;
  unsigned short* Bh = Al + 64 * 72;
  unsigned short* Bl = Bh + 64 * 72;

  const float *Ap, *Bp; float ksc; bool jobA;
  int m0, n0;
  if (bid < 96) { jobA = true;  int mt = bid % 24, nt = bid / 24; m0 = mt * 64; n0 = nt * 64;
                  Ap = y;  Bp = Wm; ksc = -K_SCALE; }
  else          { jobA = false; int t = bid - 96; int mt = t & 3, nt = t >> 2; m0 = mt * 64; n0 = nt * 64;
                  Ap = Wm; Bp = x;  ksc =  K_SCALE; }

  const int r = tid >> 2, kq = (tid & 3) * 16;
  const int w = tid >> 6, lane = tid & 63, quad = lane >> 4, l15 = lane & 15;
  const int mo = (w & 1) * 32, no = (w >> 1) * 32;   // wave tile 32x32
  f32x4 acc[2][2] = {};

  for (int kc = 0; kc < Fn; kc += 64) {
    __syncthreads();
    {
      const float* ap = Ap + ((size_t)(m0 + r)) * Fn + kc + kq;
      unsigned short hi[16], lo[16];
      #pragma unroll
      for (int q = 0; q < 4; ++q) {
        float4 v = *(const float4*)(ap + q * 4);
        float vv[4] = {v.x, v.y, v.z, v.w};
        #pragma unroll
        for (int i = 0; i < 4; ++i) {
          hi[q * 4 + i] = bf16rn(vv[i]);
          lo[q * 4 + i] = bf16rn(vv[i] - bf16tof(hi[q * 4 + i]));
        }
      }
      *(uint4*)&Ah[r * 72 + kq] = *(uint4*)&hi[0]; *(uint4*)&Ah[r * 72 + kq + 8] = *(uint4*)&hi[8];
      *(uint4*)&Al[r * 72 + kq] = *(uint4*)&lo[0]; *(uint4*)&Al[r * 72 + kq + 8] = *(uint4*)&lo[8];
    }
    {
      const float* bp = Bp + ((size_t)(n0 + r)) * Fn + kc + kq;
      unsigned short hi[16], lo[16];
      #pragma unroll
      for (int q = 0; q < 4; ++q) {
        float4 v = *(const float4*)(bp + q * 4);
        float vv[4] = {v.x, v.y, v.z, v.w};
        #pragma unroll
        for (int i = 0; i < 4; ++i) {
          hi[q * 4 + i] = bf16rn(vv[i]);
          lo[q * 4 + i] = bf16rn(vv[i] - bf16tof(hi[q * 4 + i]));
        }
      }
      *(uint4*)&Bh[r * 72 + kq] = *(uint4*)&hi[0]; *(uint4*)&Bh[r * 72 + kq + 8] = *(uint4*)&hi[8];
      *(uint4*)&Bl[r * 72 + kq] = *(uint4*)&lo[0]; *(uint4*)&Bl[r * 72 + kq + 8] = *(uint4*)&lo[8];
    }
    __syncthreads();
    #pragma unroll
    for (int ko = 0; ko < 64; ko += 32) {
      bf16x8 ah[2], al[2], bh[2], bl[2];
      #pragma unroll
      for (int mi = 0; mi < 2; ++mi) {
        int ra = (mo + mi * 16 + l15) * 72 + ko + quad * 8;
        ah[mi] = *(const bf16x8*)&Ah[ra]; al[mi] = *(const bf16x8*)&Al[ra];
      }
      #pragma unroll
      for (int nj = 0; nj < 2; ++nj) {
        int rb = (no + nj * 16 + l15) * 72 + ko + quad * 8;
        bh[nj] = *(const bf16x8*)&Bh[rb]; bl[nj] = *(const bf16x8*)&Bl[rb];
      }
      #pragma unroll
      for (int mi = 0; mi < 2; ++mi)
        #pragma unroll
        for (int nj = 0; nj < 2; ++nj) {
          acc[mi][nj] = __builtin_amdgcn_mfma_f32_16x16x32_bf16(ah[mi], bh[nj], acc[mi][nj], 0, 0, 0);
          acc[mi][nj] = __builtin_amdgcn_mfma_f32_16x16x32_bf16(ah[mi], bl[nj], acc[mi][nj], 0, 0, 0);
          acc[mi][nj] = __builtin_amdgcn_mfma_f32_16x16x32_bf16(al[mi], bh[nj], acc[mi][nj], 0, 0, 0);
        }
    }
  }
  const int bb = n0 / LXn;
  #pragma unroll
  for (int mi = 0; mi < 2; ++mi)
    #pragma unroll
    for (int nj = 0; nj < 2; ++nj)
      #pragma unroll
      for (int rr = 0; rr < 4; ++rr) {
        int row = m0 + mo + mi * 16 + quad * 4 + rr;
        int col = n0 + no + nj * 16 + l15;
        float val = __builtin_amdgcn_exp2f(ksc * acc[mi][nj][rr]);
        if (jobA) ey[(size_t)row * Hn + col] = val;
        else      exT[(size_t)bb * Hn * LXn + (size_t)row * LXn + (col - bb * LXn)] = val;
      }
}

// ---------------------------------------------------------------- kernel 2
// Fused: score (VALU-balanced, 4-way rcp pairing) + block softmax + MFMA qtm.
// 256 blocks x 768 threads (1 block/CU, 12 waves).
__global__ __launch_bounds__(768) void score_qtm(
    const float* __restrict__ exT, const float* __restrict__ ey,
    const float* __restrict__ vm,
    const unsigned short* __restrict__ xTh, const unsigned short* __restrict__ xTl,
    float* __restrict__ out)
{
  __shared__ float ey6[6 * 256];
  __shared__ float vms[256];
  __shared__ __align__(16) float part[4 * 6 * 384];
  __shared__ float red[768];
  __shared__ float red2[2][48];
  __shared__ __align__(16) unsigned short ah_s[6 * 392];  // a hi-plane (bf16)
  __shared__ __align__(16) unsigned short al_s[6 * 392];  // stride 392 breaks pow-2 banks

  const int tid = threadIdx.x;
  const int b = blockIdx.y, j0 = blockIdx.x * 6;
  const int lq = tid % 96, hg = tid / 96;
  const int hb = hg * 32;

  for (int i = tid; i < 6 * 256; i += 768)
    ey6[i] = ey[(size_t)(b * LYn + j0 + (i >> 8)) * Hn + (i & 255)];
  if (tid < 256) vms[tid] = -2.0f * vm[tid];
  __syncthreads();

  // ---- phase B: scores ----
  const float* exb = exT + (size_t)b * Hn * LXn + (size_t)hb * LXn + lq * 4;
  float acc[6][4] = {};
  for (int hs = 0; hs < 32; hs += 4) {
    float4 e0 = *(const float4*)(exb + (size_t)(hs + 0) * LXn);
    float4 e1 = *(const float4*)(exb + (size_t)(hs + 1) * LXn);
    float4 e2 = *(const float4*)(exb + (size_t)(hs + 2) * LXn);
    float4 e3 = *(const float4*)(exb + (size_t)(hs + 3) * LXn);
    const float* E0 = (const float*)&e0; const float* E1 = (const float*)&e1;
    const float* E2 = (const float*)&e2; const float* E3 = (const float*)&e3;
    float4 v4 = *(const float4*)&vms[hb + hs];
    #pragma unroll
    for (int j = 0; j < 6; ++j) {
      float4 y4 = *(const float4*)&ey6[j * 256 + hb + hs];
      #pragma unroll
      for (int i = 0; i < 4; ++i) {
        float A = fmaf(E0[i], y4.x, 1.f), B = fmaf(E1[i], y4.y, 1.f);
        float C = fmaf(E2[i], y4.z, 1.f), D = fmaf(E3[i], y4.w, 1.f);
        float AB = A * B, CD = C * D;
        float n1 = fmaf(v4.y, A, v4.x * B), n2 = fmaf(v4.w, C, v4.z * D);
        float num = fmaf(n2, AB, n1 * CD);
        acc[j][i] = fmaf(num, __builtin_amdgcn_rcpf(AB * CD), acc[j][i]);
      }
    }
  }

  // ---- fold partials 8 -> 4 -> 1 ----
  if (hg >= 4) {
    #pragma unroll
    for (int j = 0; j < 6; ++j)
      *(float4*)&part[((hg - 4) * 6 + j) * 384 + lq * 4] = *(const float4*)&acc[j][0];
  }
  __syncthreads();
  if (hg < 4) {
    #pragma unroll
    for (int j = 0; j < 6; ++j) {
      float4 o = *(const float4*)&part[(hg * 6 + j) * 384 + lq * 4];
      acc[j][0] += o.x; acc[j][1] += o.y; acc[j][2] += o.z; acc[j][3] += o.w;
      *(float4*)&part[(hg * 6 + j) * 384 + lq * 4] = *(const float4*)&acc[j][0];
    }
  }
  __syncthreads();

  // ---- phase C: softmax, write a to LDS as bf16 hi/lo ----
  float4 s4 = make_float4(0, 0, 0, 0);
  if (tid < 576) {
    const int j = tid / 96;
    #pragma unroll
    for (int p = 0; p < 4; ++p) {
      float4 o = *(const float4*)&part[(p * 6 + j) * 384 + lq * 4];
      s4.x += o.x; s4.y += o.y; s4.z += o.z; s4.w += o.w;
    }
    red[tid] = fmaxf(fmaxf(s4.x, s4.y), fmaxf(s4.z, s4.w));
  }
  __syncthreads();
  if (tid < 48) {
    const int j = tid / 8, seg = tid % 8;
    float m = red[j * 96 + seg * 12];
    #pragma unroll
    for (int i = 1; i < 12; ++i) m = fmaxf(m, red[j * 96 + seg * 12 + i]);
    red2[0][tid] = m;
  }
  __syncthreads();
  float4 e4;
  if (tid < 576) {
    const int j = tid / 96;
    float m = red2[0][j * 8];
    #pragma unroll
    for (int i = 1; i < 8; ++i) m = fmaxf(m, red2[0][j * 8 + i]);
    e4.x = __builtin_amdgcn_exp2f((s4.x - m) * LOG2E);
    e4.y = __builtin_amdgcn_exp2f((s4.y - m) * LOG2E);
    e4.z = __builtin_amdgcn_exp2f((s4.z - m) * LOG2E);
    e4.w = __builtin_amdgcn_exp2f((s4.w - m) * LOG2E);
    red[tid] = e4.x + e4.y + e4.z + e4.w;
  }
  __syncthreads();
  if (tid < 48) {
    const int j = tid / 8, seg = tid % 8;
    float t = 0.f;
    #pragma unroll
    for (int i = 0; i < 12; ++i) t += red[j * 96 + seg * 12 + i];
    red2[1][tid] = t;
  }
  __syncthreads();
  if (tid < 576) {
    const int j = tid / 96;
    float tot = 0.f;
    #pragma unroll
    for (int i = 0; i < 8; ++i) tot += red2[1][j * 8 + i];
    float r = __builtin_amdgcn_rcpf(tot);
    unsigned short h[4], l[4];
    const float* ep = (const float*)&e4;
    #pragma unroll
    for (int i = 0; i < 4; ++i) {
      float a = ep[i] * r;
      h[i] = bf16rn(a);
      l[i] = bf16rn(a - bf16tof(h[i]));
    }
    *(uint2*)&ah_s[j * 392 + lq * 4] = *(uint2*)&h[0];
    *(uint2*)&al_s[j * 392 + lq * 4] = *(uint2*)&l[0];
  }
  __syncthreads();

  // ---- phase D: out[j0+j, f] = sum_l a[j,l]*x[l,f], MFMA 3-product ----
  // waves 0-7: wave owns 64 f = 4 n-subtiles of 16. A-frag rows = j (6 valid).
  const int wv = tid >> 6;
  if (wv < 8) {
    const int lane = tid & 63, quad = lane >> 4, l15 = lane & 15;
    const int f0w = wv * 64;
    const bf16x8 zed = {0, 0, 0, 0, 0, 0, 0, 0};
    const int mrow = (l15 < 6 ? l15 : 0) * 392;
    const size_t brow = ((size_t)(b * Fn + f0w + l15)) * LXn;
    f32x4 dacc[4] = {};
    for (int ks = 0; ks < 12; ++ks) {
      const int k = ks * 32 + quad * 8;
      bf16x8 a_h = *(const bf16x8*)&ah_s[mrow + k];
      bf16x8 a_l = *(const bf16x8*)&al_s[mrow + k];
      if (l15 >= 6) { a_h = zed; a_l = zed; }
      #pragma unroll
      for (int nj = 0; nj < 4; ++nj) {
        const size_t bo = brow + (size_t)nj * 16 * LXn + k;
        bf16x8 b_h = *(const bf16x8*)&xTh[bo];
        bf16x8 b_l = *(const bf16x8*)&xTl[bo];
        dacc[nj] = __builtin_amdgcn_mfma_f32_16x16x32_bf16(a_h, b_h, dacc[nj], 0, 0, 0);
        dacc[nj] = __builtin_amdgcn_mfma_f32_16x16x32_bf16(a_l, b_h, dacc[nj], 0, 0, 0);
        dacc[nj] = __builtin_amdgcn_mfma_f32_16x16x32_bf16(a_h, b_l, dacc[nj], 0, 0, 0);
      }
    }
    #pragma unroll
    for (int nj = 0; nj < 4; ++nj)
      #pragma unroll
      for (int rr = 0; rr < 4; ++rr) {
        int row = quad * 4 + rr;                 // j index
        if (row < 6)
          out[((size_t)(b * LYn + j0 + row)) * Fn + f0w + nj * 16 + l15] = dacc[nj][rr];
      }
  }
}

extern "C" void kernel_launch(void* const* d_in, const int* in_sizes, int n_in,
                              void* d_out, int out_size, void* d_ws, size_t ws_size,
                              hipStream_t stream) {
  const float* x  = (const float*)d_in[0];
  const float* y  = (const float*)d_in[1];
  const float* Wm = (const float*)d_in[2];
  const float* vm = (const float*)d_in[3];
  float* outp = (float*)d_out;

  float* ey  = (float*)d_ws;                            // 393216 f32
  float* exT = ey + 393216;                             // 393216 f32
  unsigned short* xTh = (unsigned short*)(exT + 393216);  // 786432 us
  unsigned short* xTl = xTh + 786432;                     // 786432 us (~6.3 MB)

  hipLaunchKernelGGL(k1, dim3(384), dim3(256), 0, stream, x, y, Wm, ey, exT, xTh, xTl);
  hipLaunchKernelGGL(score_qtm, dim3(64, 4), dim3(768), 0, stream,
                     exT, ey, vm, xTh, xTl, outp);
}

// Round 9
// 105.586 us; speedup vs baseline: 1.1083x; 1.0925x over previous
//
#include <hip/hip_runtime.h>

#define LOG2E 1.4426950408889634f
#define K_SCALE 2.8853900817779268f   // 2*log2(e)

typedef __attribute__((ext_vector_type(8))) short bf16x8;
typedef __attribute__((ext_vector_type(4))) float f32x4;

constexpr int Bn = 4, LXn = 384, LYn = 384, Hn = 256, Fn = 512;

__device__ inline unsigned short bf16rn(float f) {
  unsigned u = __builtin_bit_cast(unsigned, f);
  u += 0x7fff + ((u >> 16) & 1);             // round-to-nearest-even
  return (unsigned short)(u >> 16);
}
__device__ inline float bf16tof(unsigned short h) {
  return __builtin_bit_cast(float, (unsigned)h << 16);
}

// ---------------------------------------------------------------- kernel 1
// One-shot f32 -> bf16 hi/lo split of y, Wm, x (row-major planes), plus
// transposed xT planes for qtm's B operand. Memory-bound (~33 MB traffic).
__global__ __launch_bounds__(256) void split_k(
    const float* __restrict__ x, const float* __restrict__ y,
    const float* __restrict__ Wm,
    unsigned short* __restrict__ yh, unsigned short* __restrict__ yl,
    unsigned short* __restrict__ wh, unsigned short* __restrict__ wl,
    unsigned short* __restrict__ xh, unsigned short* __restrict__ xl,
    unsigned short* __restrict__ xTh, unsigned short* __restrict__ xTl)
{
  const int tid = threadIdx.x;
  const int bid = blockIdx.x;

  if (bid < 256) {                        // ---- elementwise split path ----
    for (int q = bid * 256 + tid; q < 425984; q += 65536) {
      const float* src; unsigned short *dh, *dl; size_t off;
      if (q < 196608)      { off = (size_t)q * 4;            src = y  + off; dh = yh; dl = yl; }
      else if (q < 229376) { off = (size_t)(q - 196608) * 4; src = Wm + off; dh = wh; dl = wl; }
      else                 { off = (size_t)(q - 229376) * 4; src = x  + off; dh = xh; dl = xl; }
      float4 v = *(const float4*)src;
      const float* vv = (const float*)&v;
      unsigned short h[4], l[4];
      #pragma unroll
      for (int i = 0; i < 4; ++i) {
        h[i] = bf16rn(vv[i]);
        l[i] = bf16rn(vv[i] - bf16tof(h[i]));
      }
      *(uint2*)&dh[off] = *(uint2*)&h[0];
      *(uint2*)&dl[off] = *(uint2*)&l[0];
    }
    return;
  }

  // ---- x transpose path: 192 blocks, 64x64 tiles ----
  __shared__ float T[64 * 65];
  const int pid = bid - 256;
  const int b = pid / 48, t = pid % 48;
  const int l0 = (t / 8) * 64, f0 = (t % 8) * 64;
  const int r = tid >> 2, cq = (tid & 3) * 16;
  const float* xp = x + ((size_t)(b * LXn + l0 + r)) * Fn + f0 + cq;
  #pragma unroll
  for (int q = 0; q < 4; ++q) {
    float4 v = *(const float4*)(xp + q * 4);
    T[r * 65 + cq + q * 4 + 0] = v.x; T[r * 65 + cq + q * 4 + 1] = v.y;
    T[r * 65 + cq + q * 4 + 2] = v.z; T[r * 65 + cq + q * 4 + 3] = v.w;
  }
  __syncthreads();
  const int fr = tid >> 2, lq = (tid & 3) * 16;
  unsigned short hi[16], lo[16];
  #pragma unroll
  for (int i = 0; i < 16; ++i) {
    float v = T[(lq + i) * 65 + fr];
    hi[i] = bf16rn(v);
    lo[i] = bf16rn(v - bf16tof(hi[i]));
  }
  size_t o = ((size_t)(b * Fn + f0 + fr)) * LXn + l0 + lq;
  *(uint4*)&xTh[o] = *(uint4*)&hi[0]; *(uint4*)&xTh[o + 8] = *(uint4*)&hi[8];
  *(uint4*)&xTl[o] = *(uint4*)&lo[0]; *(uint4*)&xTl[o + 8] = *(uint4*)&lo[8];
}

// ---------------------------------------------------------------- kernel 2
// 3-product MFMA GEMM from pre-split planes, 32x32 tiles, exp2 epilogue.
// 768 blocks x 256 thr (4 waves, each one 16x16 quadrant) = 3 blocks/CU.
//  t<384:  ey[(b,j)][h] = exp2(-K * y.Wm^T)   (A=y planes, B=Wm planes)
//  t>=384: exT[b][h][l] = exp2(+K * Wm.x^T)   (A=Wm planes, B=x planes)
__global__ __launch_bounds__(256) void gemm3(
    const unsigned short* __restrict__ yh, const unsigned short* __restrict__ yl,
    const unsigned short* __restrict__ wh, const unsigned short* __restrict__ wl,
    const unsigned short* __restrict__ xh, const unsigned short* __restrict__ xl,
    float* __restrict__ ey, float* __restrict__ exT)
{
  __shared__ unsigned short Ah[32 * 72], Al[32 * 72], Bh[32 * 72], Bl[32 * 72];
  int t = blockIdx.x;
  const unsigned short *Aph, *Apl, *Bph, *Bpl;
  int m0, n0; float ksc; bool jobA;
  if (t < 384) { jobA = true;  m0 = (t % 48) * 32; n0 = (t / 48) * 32;
                 Aph = yh; Apl = yl; Bph = wh; Bpl = wl; ksc = -K_SCALE; }
  else { t -= 384; jobA = false; m0 = (t & 7) * 32; n0 = (t >> 3) * 32;
                 Aph = wh; Apl = wl; Bph = xh; Bpl = xl; ksc =  K_SCALE; }

  const int tid = threadIdx.x;
  const int r = tid >> 3, k8 = (tid & 7) * 8;     // staging: 32 rows x 64 k, 8 bf16/thread
  const int w = tid >> 6, lane = tid & 63, quad = lane >> 4, l15 = lane & 15;
  const int mo = (w & 1) * 16, no = (w >> 1) * 16;
  f32x4 acc = {};

  for (int kc = 0; kc < Fn; kc += 64) {
    __syncthreads();
    *(uint4*)&Ah[r * 72 + k8] = *(const uint4*)&Aph[(size_t)(m0 + r) * Fn + kc + k8];
    *(uint4*)&Al[r * 72 + k8] = *(const uint4*)&Apl[(size_t)(m0 + r) * Fn + kc + k8];
    *(uint4*)&Bh[r * 72 + k8] = *(const uint4*)&Bph[(size_t)(n0 + r) * Fn + kc + k8];
    *(uint4*)&Bl[r * 72 + k8] = *(const uint4*)&Bpl[(size_t)(n0 + r) * Fn + kc + k8];
    __syncthreads();
    #pragma unroll
    for (int ko = 0; ko < 64; ko += 32) {
      const int ra = (mo + l15) * 72 + ko + quad * 8;
      const int rb = (no + l15) * 72 + ko + quad * 8;
      bf16x8 a_h = *(const bf16x8*)&Ah[ra], a_l = *(const bf16x8*)&Al[ra];
      bf16x8 b_h = *(const bf16x8*)&Bh[rb], b_l = *(const bf16x8*)&Bl[rb];
      acc = __builtin_amdgcn_mfma_f32_16x16x32_bf16(a_h, b_h, acc, 0, 0, 0);
      acc = __builtin_amdgcn_mfma_f32_16x16x32_bf16(a_l, b_h, acc, 0, 0, 0);
      acc = __builtin_amdgcn_mfma_f32_16x16x32_bf16(a_h, b_l, acc, 0, 0, 0);
    }
  }
  #pragma unroll
  for (int rr = 0; rr < 4; ++rr) {
    int row = m0 + mo + quad * 4 + rr;
    int col = n0 + no + l15;
    float val = __builtin_amdgcn_exp2f(ksc * acc[rr]);
    if (jobA) ey[(size_t)row * Hn + col] = val;
    else {
      int bb = col / LXn, l = col % LXn;          // 32 | 384: tile never straddles b
      exT[(size_t)bb * Hn * LXn + (size_t)row * LXn + l] = val;
    }
  }
}

// ---------------------------------------------------------------- kernel 3
// score_v3: TJ=3, 384 thr, 512 blocks (2/CU so blocks overlap each other's
// barrier stalls). thread = (lq -> 4 l's, hg -> 64 h's). 4-way rcp pairing.
// Fused block softmax; a written to global as bf16 hi/lo planes.
__global__ __launch_bounds__(384) void score_v3(
    const float* __restrict__ exT, const float* __restrict__ ey,
    const float* __restrict__ vm, unsigned short* __restrict__ ahi,
    unsigned short* __restrict__ alo)
{
  __shared__ float ey3[3 * 256];
  __shared__ float vms[256];
  __shared__ __align__(16) float part[2 * 3 * 384];
  __shared__ float red[384];
  __shared__ float red2[2][24];

  const int tid = threadIdx.x;
  const int b = blockIdx.y, j0 = blockIdx.x * 3;
  const int lq = tid % 96, hg = tid / 96;
  const int hb = hg * 64;

  for (int i = tid; i < 3 * 256; i += 384)
    ey3[i] = ey[(size_t)(b * LYn + j0 + (i >> 8)) * Hn + (i & 255)];
  if (tid < 256) vms[tid] = -2.0f * vm[tid];
  __syncthreads();

  // ---- scores ----
  const float* exb = exT + (size_t)b * Hn * LXn + (size_t)hb * LXn + lq * 4;
  float acc[3][4] = {};
  for (int hs = 0; hs < 64; hs += 4) {
    float4 e0 = *(const float4*)(exb + (size_t)(hs + 0) * LXn);
    float4 e1 = *(const float4*)(exb + (size_t)(hs + 1) * LXn);
    float4 e2 = *(const float4*)(exb + (size_t)(hs + 2) * LXn);
    float4 e3 = *(const float4*)(exb + (size_t)(hs + 3) * LXn);
    const float* E0 = (const float*)&e0; const float* E1 = (const float*)&e1;
    const float* E2 = (const float*)&e2; const float* E3 = (const float*)&e3;
    float4 v4 = *(const float4*)&vms[hb + hs];
    #pragma unroll
    for (int j = 0; j < 3; ++j) {
      float4 y4 = *(const float4*)&ey3[j * 256 + hb + hs];
      #pragma unroll
      for (int i = 0; i < 4; ++i) {
        float A = fmaf(E0[i], y4.x, 1.f), B = fmaf(E1[i], y4.y, 1.f);
        float C = fmaf(E2[i], y4.z, 1.f), D = fmaf(E3[i], y4.w, 1.f);
        float AB = A * B, CD = C * D;
        float n1 = fmaf(v4.y, A, v4.x * B), n2 = fmaf(v4.w, C, v4.z * D);
        float num = fmaf(n2, AB, n1 * CD);
        acc[j][i] = fmaf(num, __builtin_amdgcn_rcpf(AB * CD), acc[j][i]);
      }
    }
  }

  // ---- fold 4 hg-planes -> 2 -> (final in softmax stage) ----
  if (hg >= 2) {
    #pragma unroll
    for (int j = 0; j < 3; ++j)
      *(float4*)&part[((hg - 2) * 3 + j) * 384 + lq * 4] = *(const float4*)&acc[j][0];
  }
  __syncthreads();
  if (hg < 2) {
    #pragma unroll
    for (int j = 0; j < 3; ++j) {
      float4 o = *(const float4*)&part[(hg * 3 + j) * 384 + lq * 4];
      acc[j][0] += o.x; acc[j][1] += o.y; acc[j][2] += o.z; acc[j][3] += o.w;
      *(float4*)&part[(hg * 3 + j) * 384 + lq * 4] = *(const float4*)&acc[j][0];
    }
  }
  __syncthreads();

  // ---- softmax over l (288 active threads: j = tid/96) ----
  float4 s4 = make_float4(0, 0, 0, 0);
  if (tid < 288) {
    const int j = tid / 96;
    #pragma unroll
    for (int p = 0; p < 2; ++p) {
      float4 o = *(const float4*)&part[(p * 3 + j) * 384 + lq * 4];
      s4.x += o.x; s4.y += o.y; s4.z += o.z; s4.w += o.w;
    }
    red[tid] = fmaxf(fmaxf(s4.x, s4.y), fmaxf(s4.z, s4.w));
  }
  __syncthreads();
  if (tid < 24) {
    const int j = tid / 8, seg = tid % 8;
    float m = red[j * 96 + seg * 12];
    #pragma unroll
    for (int i = 1; i < 12; ++i) m = fmaxf(m, red[j * 96 + seg * 12 + i]);
    red2[0][tid] = m;
  }
  __syncthreads();
  float4 e4;
  if (tid < 288) {
    const int j = tid / 96;
    float m = red2[0][j * 8];
    #pragma unroll
    for (int i = 1; i < 8; ++i) m = fmaxf(m, red2[0][j * 8 + i]);
    e4.x = __builtin_amdgcn_exp2f((s4.x - m) * LOG2E);
    e4.y = __builtin_amdgcn_exp2f((s4.y - m) * LOG2E);
    e4.z = __builtin_amdgcn_exp2f((s4.z - m) * LOG2E);
    e4.w = __builtin_amdgcn_exp2f((s4.w - m) * LOG2E);
    red[tid] = e4.x + e4.y + e4.z + e4.w;
  }
  __syncthreads();
  if (tid < 24) {
    const int j = tid / 8, seg = tid % 8;
    float t = 0.f;
    #pragma unroll
    for (int i = 0; i < 12; ++i) t += red[j * 96 + seg * 12 + i];
    red2[1][tid] = t;
  }
  __syncthreads();
  if (tid < 288) {
    const int j = tid / 96;
    float tot = 0.f;
    #pragma unroll
    for (int i = 0; i < 8; ++i) tot += red2[1][j * 8 + i];
    float r = __builtin_amdgcn_rcpf(tot);
    unsigned short h[4], l[4];
    const float* ep = (const float*)&e4;
    #pragma unroll
    for (int i = 0; i < 4; ++i) {
      float a = ep[i] * r;
      h[i] = bf16rn(a);
      l[i] = bf16rn(a - bf16tof(h[i]));
    }
    size_t o = (size_t)(b * LYn + j0 + j) * LXn + lq * 4;
    *(uint2*)&ahi[o] = *(uint2*)&h[0];
    *(uint2*)&alo[o] = *(uint2*)&l[0];
  }
}

// ---------------------------------------------------------------- kernel 4
// (R5 qtm, verbatim) out[b,j,f] = sum_l a[j,l]*x[l,f] via LDS-staged MFMA.
__global__ __launch_bounds__(256) void qtm(
    const unsigned short* __restrict__ ahi, const unsigned short* __restrict__ alo,
    const unsigned short* __restrict__ xTh, const unsigned short* __restrict__ xTl,
    float* __restrict__ out)
{
  __shared__ char smem[36864];
  unsigned short* LAh = (unsigned short*)smem;
  unsigned short* LAl = LAh + 64 * 72;
  unsigned short* LBh = LAl + 64 * 72;
  unsigned short* LBl = LBh + 64 * 72;

  const int bid = blockIdx.x;
  const int b = bid / 48, t = bid % 48;
  const int m0 = (t % 6) * 64, n0 = (t / 6) * 64;   // m over j(384), n over f(512)
  const int tid = threadIdx.x;
  const int r = tid >> 2, kq = (tid & 3) * 16;
  const int w = tid >> 6, lane = tid & 63, quad = lane >> 4, l15 = lane & 15;
  const int mo = (w & 1) * 32, no = (w >> 1) * 32;
  f32x4 acc[2][2] = {};

  const unsigned short* Arh = ahi + ((size_t)(b * LYn + m0 + r)) * LXn + kq;
  const unsigned short* Arl = alo + ((size_t)(b * LYn + m0 + r)) * LXn + kq;
  const unsigned short* Brh = xTh + ((size_t)(b * Fn + n0 + r)) * LXn + kq;
  const unsigned short* Brl = xTl + ((size_t)(b * Fn + n0 + r)) * LXn + kq;

  for (int kc = 0; kc < LXn; kc += 64) {
    __syncthreads();
    *(uint4*)&LAh[r * 72 + kq]     = *(const uint4*)(Arh + kc);
    *(uint4*)&LAh[r * 72 + kq + 8] = *(const uint4*)(Arh + kc + 8);
    *(uint4*)&LAl[r * 72 + kq]     = *(const uint4*)(Arl + kc);
    *(uint4*)&LAl[r * 72 + kq + 8] = *(const uint4*)(Arl + kc + 8);
    *(uint4*)&LBh[r * 72 + kq]     = *(const uint4*)(Brh + kc);
    *(uint4*)&LBh[r * 72 + kq + 8] = *(const uint4*)(Brh + kc + 8);
    *(uint4*)&LBl[r * 72 + kq]     = *(const uint4*)(Brl + kc);
    *(uint4*)&LBl[r * 72 + kq + 8] = *(const uint4*)(Brl + kc + 8);
    __syncthreads();
    #pragma unroll
    for (int ko = 0; ko < 64; ko += 32) {
      bf16x8 ah[2], al[2], bh[2], bl[2];
      #pragma unroll
      for (int mi = 0; mi < 2; ++mi) {
        int ra = (mo + mi * 16 + l15) * 72 + ko + quad * 8;
        ah[mi] = *(const bf16x8*)&LAh[ra]; al[mi] = *(const bf16x8*)&LAl[ra];
      }
      #pragma unroll
      for (int nj = 0; nj < 2; ++nj) {
        int rb = (no + nj * 16 + l15) * 72 + ko + quad * 8;
        bh[nj] = *(const bf16x8*)&LBh[rb]; bl[nj] = *(const bf16x8*)&LBl[rb];
      }
      #pragma unroll
      for (int mi = 0; mi < 2; ++mi)
        #pragma unroll
        for (int nj = 0; nj < 2; ++nj) {
          acc[mi][nj] = __builtin_amdgcn_mfma_f32_16x16x32_bf16(ah[mi], bh[nj], acc[mi][nj], 0, 0, 0);
          acc[mi][nj] = __builtin_amdgcn_mfma_f32_16x16x32_bf16(ah[mi], bl[nj], acc[mi][nj], 0, 0, 0);
          acc[mi][nj] = __builtin_amdgcn_mfma_f32_16x16x32_bf16(al[mi], bh[nj], acc[mi][nj], 0, 0, 0);
        }
    }
  }
  #pragma unroll
  for (int mi = 0; mi < 2; ++mi)
    #pragma unroll
    for (int nj = 0; nj < 2; ++nj)
      #pragma unroll
      for (int rr = 0; rr < 4; ++rr) {
        int row = m0 + mo + mi * 16 + quad * 4 + rr;   // j
        int col = n0 + no + nj * 16 + l15;             // f
        out[((size_t)(b * LYn + row)) * Fn + col] = acc[mi][nj][rr];
      }
}

extern "C" void kernel_launch(void* const* d_in, const int* in_sizes, int n_in,
                              void* d_out, int out_size, void* d_ws, size_t ws_size,
                              hipStream_t stream) {
  const float* x  = (const float*)d_in[0];
  const float* y  = (const float*)d_in[1];
  const float* Wm = (const float*)d_in[2];
  const float* vm = (const float*)d_in[3];
  float* outp = (float*)d_out;

  float* ey  = (float*)d_ws;                            // 393216 f32
  float* exT = ey + 393216;                             // 393216 f32
  unsigned short* p = (unsigned short*)(exT + 393216);
  unsigned short* yh  = p;  p += 786432;                // 1536*512
  unsigned short* yl  = p;  p += 786432;
  unsigned short* wh  = p;  p += 131072;                // 256*512
  unsigned short* wl  = p;  p += 131072;
  unsigned short* xh  = p;  p += 786432;                // 1536*512
  unsigned short* xl  = p;  p += 786432;
  unsigned short* xTh = p;  p += 786432;                // 4*512*384
  unsigned short* xTl = p;  p += 786432;
  unsigned short* ahi = p;  p += 589824;                // 1536*384
  unsigned short* alo = p;                              // total ~15 MB

  hipLaunchKernelGGL(split_k, dim3(448), dim3(256), 0, stream,
                     x, y, Wm, yh, yl, wh, wl, xh, xl, xTh, xTl);
  hipLaunchKernelGGL(gemm3, dim3(768), dim3(256), 0, stream,
                     yh, yl, wh, wl, xh, xl, ey, exT);
  hipLaunchKernelGGL(score_v3, dim3(128, 4), dim3(384), 0, stream, exT, ey, vm, ahi, alo);
  hipLaunchKernelGGL(qtm, dim3(192), dim3(256), 0, stream, ahi, alo, xTh, xTl, outp);
}

// Round 10
// 100.830 us; speedup vs baseline: 1.1606x; 1.0472x over previous
//
#include <hip/hip_runtime.h>

#define LOG2E 1.4426950408889634f
#define K_SCALE 2.8853900817779268f   // 2*log2(e)

typedef __attribute__((ext_vector_type(8))) short bf16x8;
typedef __attribute__((ext_vector_type(4))) float f32x4;

constexpr int Bn = 4, LXn = 384, LYn = 384, Hn = 256, Fn = 512;

__device__ inline unsigned short bf16rn(float f) {
  unsigned u = __builtin_bit_cast(unsigned, f);
  u += 0x7fff + ((u >> 16) & 1);             // round-to-nearest-even
  return (unsigned short)(u >> 16);
}
__device__ inline float bf16tof(unsigned short h) {
  return __builtin_bit_cast(float, (unsigned)h << 16);
}

// ---------------------------------------------------------------- kernel 1
// blocks [0,192):   ey tiles 32(m=b,j)x64(n=h)  = exp2(-K * y.Wm^T)
// blocks [192,384): exT tiles 32(m=h)x64(n=b,l) = exp2(+K * Wm.x^T)
// blocks [384,576): transpose+split x -> xTh/xTl[b][f][l]
// Finer 32x64 tiles -> 384 gemm blocks (vs 192) for balance; convert-in-kernel.
__global__ __launch_bounds__(256) void gemm4(
    const float* __restrict__ x, const float* __restrict__ y,
    const float* __restrict__ Wm, float* __restrict__ ey, float* __restrict__ exT,
    unsigned short* __restrict__ xTh, unsigned short* __restrict__ xTl)
{
  __shared__ char smem[27648];
  const int tid = threadIdx.x;
  const int bid = blockIdx.x;

  if (bid >= 384) {                       // ---- transpose/split path ----
    __shared__ float T[64 * 65];
    const int pid = bid - 384;
    const int b = pid / 48, t = pid % 48;
    const int l0 = (t / 8) * 64, f0 = (t % 8) * 64;
    const int r = tid >> 2, cq = (tid & 3) * 16;
    const float* xp = x + ((size_t)(b * LXn + l0 + r)) * Fn + f0 + cq;
    #pragma unroll
    for (int q = 0; q < 4; ++q) {
      float4 v = *(const float4*)(xp + q * 4);
      T[r * 65 + cq + q * 4 + 0] = v.x; T[r * 65 + cq + q * 4 + 1] = v.y;
      T[r * 65 + cq + q * 4 + 2] = v.z; T[r * 65 + cq + q * 4 + 3] = v.w;
    }
    __syncthreads();
    const int fr = tid >> 2, lq = (tid & 3) * 16;
    unsigned short hi[16], lo[16];
    #pragma unroll
    for (int i = 0; i < 16; ++i) {
      float v = T[(lq + i) * 65 + fr];
      hi[i] = bf16rn(v);
      lo[i] = bf16rn(v - bf16tof(hi[i]));
    }
    size_t o = ((size_t)(b * Fn + f0 + fr)) * LXn + l0 + lq;
    *(uint4*)&xTh[o] = *(uint4*)&hi[0]; *(uint4*)&xTh[o + 8] = *(uint4*)&hi[8];
    *(uint4*)&xTl[o] = *(uint4*)&lo[0]; *(uint4*)&xTl[o + 8] = *(uint4*)&lo[8];
    return;
  }

  // ---- MFMA GEMM path, 32x64 tile ----
  unsigned short* Ah = (unsigned short*)smem;   // [32][72]
  unsigned short* Al = Ah + 32 * 72;
  unsigned short* Bh = Al + 32 * 72;            // [64][72]
  unsigned short* Bl = Bh + 64 * 72;

  const float *Ap, *Bp; float ksc; bool jobA;
  int m0, n0;
  if (bid < 192) { jobA = true;  m0 = (bid % 48) * 32; n0 = (bid / 48) * 64;
                   Ap = y;  Bp = Wm; ksc = -K_SCALE; }
  else { int t = bid - 192; jobA = false; m0 = (t % 8) * 32; n0 = (t / 8) * 64;
                   Ap = Wm; Bp = x;  ksc =  K_SCALE; }

  const int rA = tid >> 3, kA = (tid & 7) * 8;    // A staging: 32 rows x 64 k
  const int rB = tid >> 2, kB = (tid & 3) * 16;   // B staging: 64 rows x 64 k
  const int w = tid >> 6, lane = tid & 63, quad = lane >> 4, l15 = lane & 15;
  const int mo = (w & 1) * 16, no = (w >> 1) * 32;   // wave: 16x32 out
  f32x4 acc[2] = {};

  for (int kc = 0; kc < Fn; kc += 64) {
    __syncthreads();
    {
      const float* ap = Ap + ((size_t)(m0 + rA)) * Fn + kc + kA;
      unsigned short hi[8], lo[8];
      #pragma unroll
      for (int q = 0; q < 2; ++q) {
        float4 v = *(const float4*)(ap + q * 4);
        float vv[4] = {v.x, v.y, v.z, v.w};
        #pragma unroll
        for (int i = 0; i < 4; ++i) {
          hi[q * 4 + i] = bf16rn(vv[i]);
          lo[q * 4 + i] = bf16rn(vv[i] - bf16tof(hi[q * 4 + i]));
        }
      }
      *(uint4*)&Ah[rA * 72 + kA] = *(uint4*)&hi[0];
      *(uint4*)&Al[rA * 72 + kA] = *(uint4*)&lo[0];
    }
    {
      const float* bp = Bp + ((size_t)(n0 + rB)) * Fn + kc + kB;
      unsigned short hi[16], lo[16];
      #pragma unroll
      for (int q = 0; q < 4; ++q) {
        float4 v = *(const float4*)(bp + q * 4);
        float vv[4] = {v.x, v.y, v.z, v.w};
        #pragma unroll
        for (int i = 0; i < 4; ++i) {
          hi[q * 4 + i] = bf16rn(vv[i]);
          lo[q * 4 + i] = bf16rn(vv[i] - bf16tof(hi[q * 4 + i]));
        }
      }
      *(uint4*)&Bh[rB * 72 + kB] = *(uint4*)&hi[0]; *(uint4*)&Bh[rB * 72 + kB + 8] = *(uint4*)&hi[8];
      *(uint4*)&Bl[rB * 72 + kB] = *(uint4*)&lo[0]; *(uint4*)&Bl[rB * 72 + kB + 8] = *(uint4*)&lo[8];
    }
    __syncthreads();
    #pragma unroll
    for (int ko = 0; ko < 64; ko += 32) {
      const int ra = (mo + l15) * 72 + ko + quad * 8;
      bf16x8 a_h = *(const bf16x8*)&Ah[ra];
      bf16x8 a_l = *(const bf16x8*)&Al[ra];
      #pragma unroll
      for (int nj = 0; nj < 2; ++nj) {
        const int rb = (no + nj * 16 + l15) * 72 + ko + quad * 8;
        bf16x8 b_h = *(const bf16x8*)&Bh[rb];
        bf16x8 b_l = *(const bf16x8*)&Bl[rb];
        acc[nj] = __builtin_amdgcn_mfma_f32_16x16x32_bf16(a_h, b_h, acc[nj], 0, 0, 0);
        acc[nj] = __builtin_amdgcn_mfma_f32_16x16x32_bf16(a_l, b_h, acc[nj], 0, 0, 0);
        acc[nj] = __builtin_amdgcn_mfma_f32_16x16x32_bf16(a_h, b_l, acc[nj], 0, 0, 0);
      }
    }
  }
  #pragma unroll
  for (int nj = 0; nj < 2; ++nj)
    #pragma unroll
    for (int rr = 0; rr < 4; ++rr) {
      int row = m0 + mo + quad * 4 + rr;
      int col = n0 + no + nj * 16 + l15;
      float val = __builtin_amdgcn_exp2f(ksc * acc[nj][rr]);
      if (jobA) ey[(size_t)row * Hn + col] = val;
      else {
        int bb = col / LXn, l = col % LXn;   // 64-aligned n-tile never straddles b
        exT[(size_t)bb * Hn * LXn + (size_t)row * LXn + l] = val;
      }
    }
}

// ---------------------------------------------------------------- kernel 2
// score_v2 (R5) with h-step unrolled 4->8: 8 global b128 in flight.
__global__ __launch_bounds__(768) void score_v2(
    const float* __restrict__ exT, const float* __restrict__ ey,
    const float* __restrict__ vm, unsigned short* __restrict__ ahi,
    unsigned short* __restrict__ alo)
{
  __shared__ float ey6[6 * 256];
  __shared__ float vms[256];
  __shared__ __align__(16) float part[4 * 6 * 384];
  __shared__ float red[768];
  __shared__ float red2[2][48];

  const int tid = threadIdx.x;
  const int b = blockIdx.y, j0 = blockIdx.x * 6;
  const int lq = tid % 96, hg = tid / 96;
  const int hb = hg * 32;

  for (int i = tid; i < 6 * 256; i += 768)
    ey6[i] = ey[(size_t)(b * LYn + j0 + (i >> 8)) * Hn + (i & 255)];
  if (tid < 256) vms[tid] = -2.0f * vm[tid];
  __syncthreads();

  const float* exb = exT + (size_t)b * Hn * LXn + (size_t)hb * LXn + lq * 4;
  float acc[6][4] = {};

  for (int hs = 0; hs < 32; hs += 8) {
    float4 e[8];
    #pragma unroll
    for (int u = 0; u < 8; ++u) e[u] = *(const float4*)(exb + (size_t)(hs + u) * LXn);
    float4 va = *(const float4*)&vms[hb + hs];
    float4 vb = *(const float4*)&vms[hb + hs + 4];
    #pragma unroll
    for (int j = 0; j < 6; ++j) {
      float4 ya = *(const float4*)&ey6[j * 256 + hb + hs];
      float4 yb = *(const float4*)&ey6[j * 256 + hb + hs + 4];
      #pragma unroll
      for (int i = 0; i < 4; ++i) {
        {
          float A = fmaf(((const float*)&e[0])[i], ya.x, 1.f);
          float B = fmaf(((const float*)&e[1])[i], ya.y, 1.f);
          float C = fmaf(((const float*)&e[2])[i], ya.z, 1.f);
          float D = fmaf(((const float*)&e[3])[i], ya.w, 1.f);
          float AB = A * B, CD = C * D;
          float n1 = fmaf(va.y, A, va.x * B), n2 = fmaf(va.w, C, va.z * D);
          float num = fmaf(n2, AB, n1 * CD);
          acc[j][i] = fmaf(num, __builtin_amdgcn_rcpf(AB * CD), acc[j][i]);
        }
        {
          float A = fmaf(((const float*)&e[4])[i], yb.x, 1.f);
          float B = fmaf(((const float*)&e[5])[i], yb.y, 1.f);
          float C = fmaf(((const float*)&e[6])[i], yb.z, 1.f);
          float D = fmaf(((const float*)&e[7])[i], yb.w, 1.f);
          float AB = A * B, CD = C * D;
          float n1 = fmaf(vb.y, A, vb.x * B), n2 = fmaf(vb.w, C, vb.z * D);
          float num = fmaf(n2, AB, n1 * CD);
          acc[j][i] = fmaf(num, __builtin_amdgcn_rcpf(AB * CD), acc[j][i]);
        }
      }
    }
  }

  if (hg >= 4) {
    #pragma unroll
    for (int j = 0; j < 6; ++j)
      *(float4*)&part[((hg - 4) * 6 + j) * 384 + lq * 4] = *(const float4*)&acc[j][0];
  }
  __syncthreads();
  if (hg < 4) {
    #pragma unroll
    for (int j = 0; j < 6; ++j) {
      float4 o = *(const float4*)&part[(hg * 6 + j) * 384 + lq * 4];
      acc[j][0] += o.x; acc[j][1] += o.y; acc[j][2] += o.z; acc[j][3] += o.w;
      *(float4*)&part[(hg * 6 + j) * 384 + lq * 4] = *(const float4*)&acc[j][0];
    }
  }
  __syncthreads();

  float4 s4 = make_float4(0, 0, 0, 0);
  if (tid < 576) {
    const int j = tid / 96;
    #pragma unroll
    for (int p = 0; p < 4; ++p) {
      float4 o = *(const float4*)&part[(p * 6 + j) * 384 + lq * 4];
      s4.x += o.x; s4.y += o.y; s4.z += o.z; s4.w += o.w;
    }
    red[tid] = fmaxf(fmaxf(s4.x, s4.y), fmaxf(s4.z, s4.w));
  }
  __syncthreads();
  if (tid < 48) {
    const int j = tid / 8, seg = tid % 8;
    float m = red[j * 96 + seg * 12];
    #pragma unroll
    for (int i = 1; i < 12; ++i) m = fmaxf(m, red[j * 96 + seg * 12 + i]);
    red2[0][tid] = m;
  }
  __syncthreads();
  float4 e4;
  if (tid < 576) {
    const int j = tid / 96;
    float m = red2[0][j * 8];
    #pragma unroll
    for (int i = 1; i < 8; ++i) m = fmaxf(m, red2[0][j * 8 + i]);
    e4.x = __builtin_amdgcn_exp2f((s4.x - m) * LOG2E);
    e4.y = __builtin_amdgcn_exp2f((s4.y - m) * LOG2E);
    e4.z = __builtin_amdgcn_exp2f((s4.z - m) * LOG2E);
    e4.w = __builtin_amdgcn_exp2f((s4.w - m) * LOG2E);
    red[tid] = e4.x + e4.y + e4.z + e4.w;
  }
  __syncthreads();
  if (tid < 48) {
    const int j = tid / 8, seg = tid % 8;
    float t = 0.f;
    #pragma unroll
    for (int i = 0; i < 12; ++i) t += red[j * 96 + seg * 12 + i];
    red2[1][tid] = t;
  }
  __syncthreads();
  if (tid < 576) {
    const int j = tid / 96;
    float tot = 0.f;
    #pragma unroll
    for (int i = 0; i < 8; ++i) tot += red2[1][j * 8 + i];
    float r = __builtin_amdgcn_rcpf(tot);
    unsigned short h[4], l[4];
    const float* ep = (const float*)&e4;
    #pragma unroll
    for (int i = 0; i < 4; ++i) {
      float a = ep[i] * r;
      h[i] = bf16rn(a);
      l[i] = bf16rn(a - bf16tof(h[i]));
    }
    size_t o = (size_t)(b * LYn + j0 + j) * LXn + lq * 4;
    *(uint2*)&ahi[o] = *(uint2*)&h[0];
    *(uint2*)&alo[o] = *(uint2*)&l[0];
  }
}

// ---------------------------------------------------------------- kernel 3
// (R9 qtm verbatim) out[b,j,f] = sum_l a[j,l]*x[l,f] via LDS-staged MFMA.
__global__ __launch_bounds__(256) void qtm(
    const unsigned short* __restrict__ ahi, const unsigned short* __restrict__ alo,
    const unsigned short* __restrict__ xTh, const unsigned short* __restrict__ xTl,
    float* __restrict__ out)
{
  __shared__ char smem[36864];
  unsigned short* LAh = (unsigned short*)smem;
  unsigned short* LAl = LAh + 64 * 72;
  unsigned short* LBh = LAl + 64 * 72;
  unsigned short* LBl = LBh + 64 * 72;

  const int bid = blockIdx.x;
  const int b = bid / 48, t = bid % 48;
  const int m0 = (t % 6) * 64, n0 = (t / 6) * 64;
  const int tid = threadIdx.x;
  const int r = tid >> 2, kq = (tid & 3) * 16;
  const int w = tid >> 6, lane = tid & 63, quad = lane >> 4, l15 = lane & 15;
  const int mo = (w & 1) * 32, no = (w >> 1) * 32;
  f32x4 acc[2][2] = {};

  const unsigned short* Arh = ahi + ((size_t)(b * LYn + m0 + r)) * LXn + kq;
  const unsigned short* Arl = alo + ((size_t)(b * LYn + m0 + r)) * LXn + kq;
  const unsigned short* Brh = xTh + ((size_t)(b * Fn + n0 + r)) * LXn + kq;
  const unsigned short* Brl = xTl + ((size_t)(b * Fn + n0 + r)) * LXn + kq;

  for (int kc = 0; kc < LXn; kc += 64) {
    __syncthreads();
    *(uint4*)&LAh[r * 72 + kq]     = *(const uint4*)(Arh + kc);
    *(uint4*)&LAh[r * 72 + kq + 8] = *(const uint4*)(Arh + kc + 8);
    *(uint4*)&LAl[r * 72 + kq]     = *(const uint4*)(Arl + kc);
    *(uint4*)&LAl[r * 72 + kq + 8] = *(const uint4*)(Arl + kc + 8);
    *(uint4*)&LBh[r * 72 + kq]     = *(const uint4*)(Brh + kc);
    *(uint4*)&LBh[r * 72 + kq + 8] = *(const uint4*)(Brh + kc + 8);
    *(uint4*)&LBl[r * 72 + kq]     = *(const uint4*)(Brl + kc);
    *(uint4*)&LBl[r * 72 + kq + 8] = *(const uint4*)(Brl + kc + 8);
    __syncthreads();
    #pragma unroll
    for (int ko = 0; ko < 64; ko += 32) {
      bf16x8 ah[2], al[2], bh[2], bl[2];
      #pragma unroll
      for (int mi = 0; mi < 2; ++mi) {
        int ra = (mo + mi * 16 + l15) * 72 + ko + quad * 8;
        ah[mi] = *(const bf16x8*)&LAh[ra]; al[mi] = *(const bf16x8*)&LAl[ra];
      }
      #pragma unroll
      for (int nj = 0; nj < 2; ++nj) {
        int rb = (no + nj * 16 + l15) * 72 + ko + quad * 8;
        bh[nj] = *(const bf16x8*)&LBh[rb]; bl[nj] = *(const bf16x8*)&LBl[rb];
      }
      #pragma unroll
      for (int mi = 0; mi < 2; ++mi)
        #pragma unroll
        for (int nj = 0; nj < 2; ++nj) {
          acc[mi][nj] = __builtin_amdgcn_mfma_f32_16x16x32_bf16(ah[mi], bh[nj], acc[mi][nj], 0, 0, 0);
          acc[mi][nj] = __builtin_amdgcn_mfma_f32_16x16x32_bf16(ah[mi], bl[nj], acc[mi][nj], 0, 0, 0);
          acc[mi][nj] = __builtin_amdgcn_mfma_f32_16x16x32_bf16(al[mi], bh[nj], acc[mi][nj], 0, 0, 0);
        }
    }
  }
  #pragma unroll
  for (int mi = 0; mi < 2; ++mi)
    #pragma unroll
    for (int nj = 0; nj < 2; ++nj)
      #pragma unroll
      for (int rr = 0; rr < 4; ++rr) {
        int row = m0 + mo + mi * 16 + quad * 4 + rr;
        int col = n0 + no + nj * 16 + l15;
        out[((size_t)(b * LYn + row)) * Fn + col] = acc[mi][nj][rr];
      }
}

extern "C" void kernel_launch(void* const* d_in, const int* in_sizes, int n_in,
                              void* d_out, int out_size, void* d_ws, size_t ws_size,
                              hipStream_t stream) {
  const float* x  = (const float*)d_in[0];
  const float* y  = (const float*)d_in[1];
  const float* Wm = (const float*)d_in[2];
  const float* vm = (const float*)d_in[3];
  float* outp = (float*)d_out;

  float* ey  = (float*)d_ws;                              // 393216 f32
  float* exT = ey + 393216;                               // 393216 f32
  unsigned short* xTh = (unsigned short*)(exT + 393216);  // 786432 us
  unsigned short* xTl = xTh + 786432;
  unsigned short* ahi = xTl + 786432;                     // 589824 us
  unsigned short* alo = ahi + 589824;                     // total ~8.6 MB

  hipLaunchKernelGGL(gemm4, dim3(576), dim3(256), 0, stream, x, y, Wm, ey, exT, xTh, xTl);
  hipLaunchKernelGGL(score_v2, dim3(64, 4), dim3(768), 0, stream, exT, ey, vm, ahi, alo);
  hipLaunchKernelGGL(qtm, dim3(192), dim3(256), 0, stream, ahi, alo, xTh, xTl, outp);
}

// Round 11
// 96.213 us; speedup vs baseline: 1.2163x; 1.0480x over previous
//
#include <hip/hip_runtime.h>

#define LOG2E 1.4426950408889634f
#define K_SCALE 2.8853900817779268f   // 2*log2(e)

typedef __attribute__((ext_vector_type(8))) short bf16x8;
typedef __attribute__((ext_vector_type(4))) float f32x4;

constexpr int Bn = 4, LXn = 384, LYn = 384, Hn = 256, Fn = 512;

__device__ inline unsigned short bf16rn(float f) {
  unsigned u = __builtin_bit_cast(unsigned, f);
  u += 0x7fff + ((u >> 16) & 1);             // round-to-nearest-even
  return (unsigned short)(u >> 16);
}
__device__ inline float bf16tof(unsigned short h) {
  return __builtin_bit_cast(float, (unsigned)h << 16);
}

// ---------------------------------------------------------------- kernel 1
// blocks [0,192):   ey tiles 32(m=b,j)x64(n=h)  = exp2(-K * y.Wm^T)
// blocks [192,384): exT tiles 32(m=h)x64(n=b,l) = exp2(+K * Wm.x^T)
// blocks [384,576): transpose+split x -> xTh/xTl[b][f][l]
// Register-prefetch staging: next kc tile is loaded into VGPRs while MFMAs
// consume the current LDS tile (hides ~350cy global latency per kc).
__global__ __launch_bounds__(256) void gemm4(
    const float* __restrict__ x, const float* __restrict__ y,
    const float* __restrict__ Wm, float* __restrict__ ey, float* __restrict__ exT,
    unsigned short* __restrict__ xTh, unsigned short* __restrict__ xTl)
{
  __shared__ char smem[27648];
  const int tid = threadIdx.x;
  const int bid = blockIdx.x;

  if (bid >= 384) {                       // ---- transpose/split path ----
    __shared__ float T[64 * 65];
    const int pid = bid - 384;
    const int b = pid / 48, t = pid % 48;
    const int l0 = (t / 8) * 64, f0 = (t % 8) * 64;
    const int r = tid >> 2, cq = (tid & 3) * 16;
    const float* xp = x + ((size_t)(b * LXn + l0 + r)) * Fn + f0 + cq;
    #pragma unroll
    for (int q = 0; q < 4; ++q) {
      float4 v = *(const float4*)(xp + q * 4);
      T[r * 65 + cq + q * 4 + 0] = v.x; T[r * 65 + cq + q * 4 + 1] = v.y;
      T[r * 65 + cq + q * 4 + 2] = v.z; T[r * 65 + cq + q * 4 + 3] = v.w;
    }
    __syncthreads();
    const int fr = tid >> 2, lq = (tid & 3) * 16;
    unsigned short hi[16], lo[16];
    #pragma unroll
    for (int i = 0; i < 16; ++i) {
      float v = T[(lq + i) * 65 + fr];
      hi[i] = bf16rn(v);
      lo[i] = bf16rn(v - bf16tof(hi[i]));
    }
    size_t o = ((size_t)(b * Fn + f0 + fr)) * LXn + l0 + lq;
    *(uint4*)&xTh[o] = *(uint4*)&hi[0]; *(uint4*)&xTh[o + 8] = *(uint4*)&hi[8];
    *(uint4*)&xTl[o] = *(uint4*)&lo[0]; *(uint4*)&xTl[o + 8] = *(uint4*)&lo[8];
    return;
  }

  // ---- MFMA GEMM path, 32x64 tile ----
  unsigned short* Ah = (unsigned short*)smem;   // [32][72]
  unsigned short* Al = Ah + 32 * 72;
  unsigned short* Bh = Al + 32 * 72;            // [64][72]
  unsigned short* Bl = Bh + 64 * 72;

  const float *Ap, *Bp; float ksc; bool jobA;
  int m0, n0;
  if (bid < 192) { jobA = true;  m0 = (bid % 48) * 32; n0 = (bid / 48) * 64;
                   Ap = y;  Bp = Wm; ksc = -K_SCALE; }
  else { int t = bid - 192; jobA = false; m0 = (t % 8) * 32; n0 = (t / 8) * 64;
                   Ap = Wm; Bp = x;  ksc =  K_SCALE; }

  const int rA = tid >> 3, kA = (tid & 7) * 8;    // A staging: 32 rows x 64 k
  const int rB = tid >> 2, kB = (tid & 3) * 16;   // B staging: 64 rows x 64 k
  const int w = tid >> 6, lane = tid & 63, quad = lane >> 4, l15 = lane & 15;
  const int mo = (w & 1) * 16, no = (w >> 1) * 32;   // wave: 16x32 out
  f32x4 acc[2] = {};

  const float* apt = Ap + ((size_t)(m0 + rA)) * Fn + kA;
  const float* bpt = Bp + ((size_t)(n0 + rB)) * Fn + kB;
  float4 aR0 = *(const float4*)(apt),     aR1 = *(const float4*)(apt + 4);
  float4 bR0 = *(const float4*)(bpt),     bR1 = *(const float4*)(bpt + 4);
  float4 bR2 = *(const float4*)(bpt + 8), bR3 = *(const float4*)(bpt + 12);

  for (int kc = 0; kc < Fn; kc += 64) {
    __syncthreads();
    {
      float av[8] = {aR0.x, aR0.y, aR0.z, aR0.w, aR1.x, aR1.y, aR1.z, aR1.w};
      unsigned short hi[8], lo[8];
      #pragma unroll
      for (int i = 0; i < 8; ++i) {
        hi[i] = bf16rn(av[i]);
        lo[i] = bf16rn(av[i] - bf16tof(hi[i]));
      }
      *(uint4*)&Ah[rA * 72 + kA] = *(uint4*)&hi[0];
      *(uint4*)&Al[rA * 72 + kA] = *(uint4*)&lo[0];
    }
    {
      float bv[16] = {bR0.x, bR0.y, bR0.z, bR0.w, bR1.x, bR1.y, bR1.z, bR1.w,
                      bR2.x, bR2.y, bR2.z, bR2.w, bR3.x, bR3.y, bR3.z, bR3.w};
      unsigned short hi[16], lo[16];
      #pragma unroll
      for (int i = 0; i < 16; ++i) {
        hi[i] = bf16rn(bv[i]);
        lo[i] = bf16rn(bv[i] - bf16tof(hi[i]));
      }
      *(uint4*)&Bh[rB * 72 + kB] = *(uint4*)&hi[0]; *(uint4*)&Bh[rB * 72 + kB + 8] = *(uint4*)&hi[8];
      *(uint4*)&Bl[rB * 72 + kB] = *(uint4*)&lo[0]; *(uint4*)&Bl[rB * 72 + kB + 8] = *(uint4*)&lo[8];
    }
    __syncthreads();
    if (kc + 64 < Fn) {                   // prefetch next tile (latency hidden below)
      aR0 = *(const float4*)(apt + kc + 64);     aR1 = *(const float4*)(apt + kc + 68);
      bR0 = *(const float4*)(bpt + kc + 64);     bR1 = *(const float4*)(bpt + kc + 68);
      bR2 = *(const float4*)(bpt + kc + 72);     bR3 = *(const float4*)(bpt + kc + 76);
    }
    #pragma unroll
    for (int ko = 0; ko < 64; ko += 32) {
      const int ra = (mo + l15) * 72 + ko + quad * 8;
      bf16x8 a_h = *(const bf16x8*)&Ah[ra];
      bf16x8 a_l = *(const bf16x8*)&Al[ra];
      #pragma unroll
      for (int nj = 0; nj < 2; ++nj) {
        const int rb = (no + nj * 16 + l15) * 72 + ko + quad * 8;
        bf16x8 b_h = *(const bf16x8*)&Bh[rb];
        bf16x8 b_l = *(const bf16x8*)&Bl[rb];
        acc[nj] = __builtin_amdgcn_mfma_f32_16x16x32_bf16(a_h, b_h, acc[nj], 0, 0, 0);
        acc[nj] = __builtin_amdgcn_mfma_f32_16x16x32_bf16(a_l, b_h, acc[nj], 0, 0, 0);
        acc[nj] = __builtin_amdgcn_mfma_f32_16x16x32_bf16(a_h, b_l, acc[nj], 0, 0, 0);
      }
    }
  }
  #pragma unroll
  for (int nj = 0; nj < 2; ++nj)
    #pragma unroll
    for (int rr = 0; rr < 4; ++rr) {
      int row = m0 + mo + quad * 4 + rr;
      int col = n0 + no + nj * 16 + l15;
      float val = __builtin_amdgcn_exp2f(ksc * acc[nj][rr]);
      if (jobA) ey[(size_t)row * Hn + col] = val;
      else {
        int bb = col / LXn, l = col % LXn;
        exT[(size_t)bb * Hn * LXn + (size_t)row * LXn + l] = val;
      }
    }
}

// ---------------------------------------------------------------- kernel 2
// score_v2 (R10, unroll-8) — a written as bf16 hi plane ONLY (a in [0,1];
// single-plane error ~2e-4 in qtm, under threshold).
__global__ __launch_bounds__(768) void score_v2(
    const float* __restrict__ exT, const float* __restrict__ ey,
    const float* __restrict__ vm, unsigned short* __restrict__ ahi)
{
  __shared__ float ey6[6 * 256];
  __shared__ float vms[256];
  __shared__ __align__(16) float part[4 * 6 * 384];
  __shared__ float red[768];
  __shared__ float red2[2][48];

  const int tid = threadIdx.x;
  const int b = blockIdx.y, j0 = blockIdx.x * 6;
  const int lq = tid % 96, hg = tid / 96;
  const int hb = hg * 32;

  for (int i = tid; i < 6 * 256; i += 768)
    ey6[i] = ey[(size_t)(b * LYn + j0 + (i >> 8)) * Hn + (i & 255)];
  if (tid < 256) vms[tid] = -2.0f * vm[tid];
  __syncthreads();

  const float* exb = exT + (size_t)b * Hn * LXn + (size_t)hb * LXn + lq * 4;
  float acc[6][4] = {};

  for (int hs = 0; hs < 32; hs += 8) {
    float4 e[8];
    #pragma unroll
    for (int u = 0; u < 8; ++u) e[u] = *(const float4*)(exb + (size_t)(hs + u) * LXn);
    float4 va = *(const float4*)&vms[hb + hs];
    float4 vb = *(const float4*)&vms[hb + hs + 4];
    #pragma unroll
    for (int j = 0; j < 6; ++j) {
      float4 ya = *(const float4*)&ey6[j * 256 + hb + hs];
      float4 yb = *(const float4*)&ey6[j * 256 + hb + hs + 4];
      #pragma unroll
      for (int i = 0; i < 4; ++i) {
        {
          float A = fmaf(((const float*)&e[0])[i], ya.x, 1.f);
          float B = fmaf(((const float*)&e[1])[i], ya.y, 1.f);
          float C = fmaf(((const float*)&e[2])[i], ya.z, 1.f);
          float D = fmaf(((const float*)&e[3])[i], ya.w, 1.f);
          float AB = A * B, CD = C * D;
          float n1 = fmaf(va.y, A, va.x * B), n2 = fmaf(va.w, C, va.z * D);
          float num = fmaf(n2, AB, n1 * CD);
          acc[j][i] = fmaf(num, __builtin_amdgcn_rcpf(AB * CD), acc[j][i]);
        }
        {
          float A = fmaf(((const float*)&e[4])[i], yb.x, 1.f);
          float B = fmaf(((const float*)&e[5])[i], yb.y, 1.f);
          float C = fmaf(((const float*)&e[6])[i], yb.z, 1.f);
          float D = fmaf(((const float*)&e[7])[i], yb.w, 1.f);
          float AB = A * B, CD = C * D;
          float n1 = fmaf(vb.y, A, vb.x * B), n2 = fmaf(vb.w, C, vb.z * D);
          float num = fmaf(n2, AB, n1 * CD);
          acc[j][i] = fmaf(num, __builtin_amdgcn_rcpf(AB * CD), acc[j][i]);
        }
      }
    }
  }

  if (hg >= 4) {
    #pragma unroll
    for (int j = 0; j < 6; ++j)
      *(float4*)&part[((hg - 4) * 6 + j) * 384 + lq * 4] = *(const float4*)&acc[j][0];
  }
  __syncthreads();
  if (hg < 4) {
    #pragma unroll
    for (int j = 0; j < 6; ++j) {
      float4 o = *(const float4*)&part[(hg * 6 + j) * 384 + lq * 4];
      acc[j][0] += o.x; acc[j][1] += o.y; acc[j][2] += o.z; acc[j][3] += o.w;
      *(float4*)&part[(hg * 6 + j) * 384 + lq * 4] = *(const float4*)&acc[j][0];
    }
  }
  __syncthreads();

  float4 s4 = make_float4(0, 0, 0, 0);
  if (tid < 576) {
    const int j = tid / 96;
    #pragma unroll
    for (int p = 0; p < 4; ++p) {
      float4 o = *(const float4*)&part[(p * 6 + j) * 384 + lq * 4];
      s4.x += o.x; s4.y += o.y; s4.z += o.z; s4.w += o.w;
    }
    red[tid] = fmaxf(fmaxf(s4.x, s4.y), fmaxf(s4.z, s4.w));
  }
  __syncthreads();
  if (tid < 48) {
    const int j = tid / 8, seg = tid % 8;
    float m = red[j * 96 + seg * 12];
    #pragma unroll
    for (int i = 1; i < 12; ++i) m = fmaxf(m, red[j * 96 + seg * 12 + i]);
    red2[0][tid] = m;
  }
  __syncthreads();
  float4 e4;
  if (tid < 576) {
    const int j = tid / 96;
    float m = red2[0][j * 8];
    #pragma unroll
    for (int i = 1; i < 8; ++i) m = fmaxf(m, red2[0][j * 8 + i]);
    e4.x = __builtin_amdgcn_exp2f((s4.x - m) * LOG2E);
    e4.y = __builtin_amdgcn_exp2f((s4.y - m) * LOG2E);
    e4.z = __builtin_amdgcn_exp2f((s4.z - m) * LOG2E);
    e4.w = __builtin_amdgcn_exp2f((s4.w - m) * LOG2E);
    red[tid] = e4.x + e4.y + e4.z + e4.w;
  }
  __syncthreads();
  if (tid < 48) {
    const int j = tid / 8, seg = tid % 8;
    float t = 0.f;
    #pragma unroll
    for (int i = 0; i < 12; ++i) t += red[j * 96 + seg * 12 + i];
    red2[1][tid] = t;
  }
  __syncthreads();
  if (tid < 576) {
    const int j = tid / 96;
    float tot = 0.f;
    #pragma unroll
    for (int i = 0; i < 8; ++i) tot += red2[1][j * 8 + i];
    float r = __builtin_amdgcn_rcpf(tot);
    unsigned short h[4];
    const float* ep = (const float*)&e4;
    #pragma unroll
    for (int i = 0; i < 4; ++i) h[i] = bf16rn(ep[i] * r);
    size_t o = (size_t)(b * LYn + j0 + j) * LXn + lq * 4;
    *(uint2*)&ahi[o] = *(uint2*)&h[0];
  }
}

// ---------------------------------------------------------------- kernel 3
// qtm, 2-product (single a-plane) + register-prefetch staging.
__global__ __launch_bounds__(256) void qtm(
    const unsigned short* __restrict__ ahi,
    const unsigned short* __restrict__ xTh, const unsigned short* __restrict__ xTl,
    float* __restrict__ out)
{
  __shared__ char smem[27648];
  unsigned short* LAh = (unsigned short*)smem;   // [64][72]
  unsigned short* LBh = LAh + 64 * 72;
  unsigned short* LBl = LBh + 64 * 72;

  const int bid = blockIdx.x;
  const int b = bid / 48, t = bid % 48;
  const int m0 = (t % 6) * 64, n0 = (t / 6) * 64;
  const int tid = threadIdx.x;
  const int r = tid >> 2, kq = (tid & 3) * 16;
  const int w = tid >> 6, lane = tid & 63, quad = lane >> 4, l15 = lane & 15;
  const int mo = (w & 1) * 32, no = (w >> 1) * 32;
  f32x4 acc[2][2] = {};

  const unsigned short* Arh = ahi + ((size_t)(b * LYn + m0 + r)) * LXn + kq;
  const unsigned short* Brh = xTh + ((size_t)(b * Fn + n0 + r)) * LXn + kq;
  const unsigned short* Brl = xTl + ((size_t)(b * Fn + n0 + r)) * LXn + kq;
  uint4 pA0 = *(const uint4*)(Arh),     pA1 = *(const uint4*)(Arh + 8);
  uint4 pH0 = *(const uint4*)(Brh),     pH1 = *(const uint4*)(Brh + 8);
  uint4 pL0 = *(const uint4*)(Brl),     pL1 = *(const uint4*)(Brl + 8);

  for (int kc = 0; kc < LXn; kc += 64) {
    __syncthreads();
    *(uint4*)&LAh[r * 72 + kq]     = pA0;  *(uint4*)&LAh[r * 72 + kq + 8] = pA1;
    *(uint4*)&LBh[r * 72 + kq]     = pH0;  *(uint4*)&LBh[r * 72 + kq + 8] = pH1;
    *(uint4*)&LBl[r * 72 + kq]     = pL0;  *(uint4*)&LBl[r * 72 + kq + 8] = pL1;
    __syncthreads();
    if (kc + 64 < LXn) {                  // prefetch next tile
      pA0 = *(const uint4*)(Arh + kc + 64); pA1 = *(const uint4*)(Arh + kc + 72);
      pH0 = *(const uint4*)(Brh + kc + 64); pH1 = *(const uint4*)(Brh + kc + 72);
      pL0 = *(const uint4*)(Brl + kc + 64); pL1 = *(const uint4*)(Brl + kc + 72);
    }
    #pragma unroll
    for (int ko = 0; ko < 64; ko += 32) {
      bf16x8 ah[2], bh[2], bl[2];
      #pragma unroll
      for (int mi = 0; mi < 2; ++mi)
        ah[mi] = *(const bf16x8*)&LAh[(mo + mi * 16 + l15) * 72 + ko + quad * 8];
      #pragma unroll
      for (int nj = 0; nj < 2; ++nj) {
        int rb = (no + nj * 16 + l15) * 72 + ko + quad * 8;
        bh[nj] = *(const bf16x8*)&LBh[rb]; bl[nj] = *(const bf16x8*)&LBl[rb];
      }
      #pragma unroll
      for (int mi = 0; mi < 2; ++mi)
        #pragma unroll
        for (int nj = 0; nj < 2; ++nj) {
          acc[mi][nj] = __builtin_amdgcn_mfma_f32_16x16x32_bf16(ah[mi], bh[nj], acc[mi][nj], 0, 0, 0);
          acc[mi][nj] = __builtin_amdgcn_mfma_f32_16x16x32_bf16(ah[mi], bl[nj], acc[mi][nj], 0, 0, 0);
        }
    }
  }
  #pragma unroll
  for (int mi = 0; mi < 2; ++mi)
    #pragma unroll
    for (int nj = 0; nj < 2; ++nj)
      #pragma unroll
      for (int rr = 0; rr < 4; ++rr) {
        int row = m0 + mo + mi * 16 + quad * 4 + rr;
        int col = n0 + no + nj * 16 + l15;
        out[((size_t)(b * LYn + row)) * Fn + col] = acc[mi][nj][rr];
      }
}

extern "C" void kernel_launch(void* const* d_in, const int* in_sizes, int n_in,
                              void* d_out, int out_size, void* d_ws, size_t ws_size,
                              hipStream_t stream) {
  const float* x  = (const float*)d_in[0];
  const float* y  = (const float*)d_in[1];
  const float* Wm = (const float*)d_in[2];
  const float* vm = (const float*)d_in[3];
  float* outp = (float*)d_out;

  float* ey  = (float*)d_ws;                              // 393216 f32
  float* exT = ey + 393216;                               // 393216 f32
  unsigned short* xTh = (unsigned short*)(exT + 393216);  // 786432 us
  unsigned short* xTl = xTh + 786432;
  unsigned short* ahi = xTl + 786432;                     // 589824 us (~7.5 MB)

  hipLaunchKernelGGL(gemm4, dim3(576), dim3(256), 0, stream, x, y, Wm, ey, exT, xTh, xTl);
  hipLaunchKernelGGL(score_v2, dim3(64, 4), dim3(768), 0, stream, exT, ey, vm, ahi);
  hipLaunchKernelGGL(qtm, dim3(192), dim3(256), 0, stream, ahi, xTh, xTl, outp);
}